// Round 6
// baseline (171.390 us; speedup 1.0000x reference)
//
#include <hip/hip_runtime.h>

typedef unsigned int u32;
typedef unsigned short u16;
typedef long long i64;

#define NNODES 50000
#define NEDGES 800000
#define DF 128
#define CAP 64      // bucket capacity: Poisson(16) tail P(c>64) ~ 1e-19/node
#define NBINS 196   // dst>>8 : 256-dst bins, 196 covers 50176
#define BINCAP 5120 // per-bin edge capacity: lambda=4096, +16 sigma
#define EPB 2048    // edges per block in bin pass
#define NBINB ((NEDGES + EPB - 1) / EPB)   // 391 bin blocks

typedef __bf16 bf16x8 __attribute__((ext_vector_type(8)));
typedef float f32x4 __attribute__((ext_vector_type(4)));
typedef float f32x2 __attribute__((ext_vector_type(2)));
typedef _Float16 f16x2 __attribute__((ext_vector_type(2)));

__device__ __forceinline__ u16 f2bf(float f) {
    union { float f; u32 i; } v; v.f = f;
    u32 u = v.i;
    return (u16)((u + 0x7fffu + ((u >> 16) & 1u)) >> 16);  // RNE
}
__device__ __forceinline__ u16 f2h(float f) {
    _Float16 h = (_Float16)f;            // v_cvt_f16_f32 (RNE)
    union { _Float16 h; u16 u; } v; v.h = h;
    return v.u;
}
__device__ __forceinline__ f32x2 h2v2(u32 w) {
    union { u32 u; f16x2 h; } v; v.u = w;
    f32x2 r; r.x = (float)v.h.x; r.y = (float)v.h.y;
    return r;                            // 2x v_cvt_f32_f16; sums use v_pk_add_f32
}

// ------- 0. init: detect dtype, zero cursors, zero nf16 pad row ---------
__global__ __launch_bounds__(256) void init_kernel(const u32* __restrict__ src_w,
                                                   u32* __restrict__ flag,
                                                   u32* __restrict__ cursors,
                                                   u16* __restrict__ nf16) {
    __shared__ int any_nz;
    int tid = threadIdx.x;
    for (int i = tid; i < NBINS * 16; i += 256) cursors[i] = 0u;
    if (tid < 64) ((u32*)(nf16 + (size_t)NNODES * DF))[tid] = 0u;  // zero pad row
    if (tid == 0) any_nz = 0;
    __syncthreads();
    if (src_w[2 * tid + 1] != 0u) atomicOr(&any_nz, 1);
    __syncthreads();
    if (tid == 0) *flag = (any_nz == 0) ? 1u : 0u;  // 1 = int64
}

// ------- 1. merged prep + bin (independent work co-scheduled) -----------
__global__ __launch_bounds__(256) void prepbin_kernel(const void* __restrict__ src,
                                                      const void* __restrict__ dst,
                                                      const u32* __restrict__ flag,
                                                      u32* __restrict__ cursors,
                                                      u32* __restrict__ binbuf,
                                                      const float* __restrict__ nfeats,
                                                      const float* __restrict__ W1,
                                                      const float* __restrict__ W2,
                                                      u16* __restrict__ nf16,
                                                      u16* __restrict__ W1T,
                                                      u16* __restrict__ W2T) {
    __shared__ u32 s_cnt[NBINS];
    __shared__ u32 s_base[NBINS];
    int bid = blockIdx.x, t = threadIdx.x;
    if (bid < NBINB) {
        for (int i = t; i < NBINS; i += 256) s_cnt[i] = 0u;
        __syncthreads();

        bool is64 = (*flag != 0u);
        int e0 = bid * EPB + t;
        u32 pk[8];
#pragma unroll
        for (int i = 0; i < 8; ++i) {
            int e = e0 + i * 256;
            pk[i] = 0xFFFFFFFFu;         // sentinel (src=0xFFFF impossible)
            if (e < NEDGES) {
                int s, d;
                if (is64) { s = (int)((const i64*)src)[e]; d = (int)((const i64*)dst)[e]; }
                else      { s = ((const int*)src)[e];      d = ((const int*)dst)[e]; }
                pk[i] = (u32)s | ((u32)d << 16);
                atomicAdd(&s_cnt[(u32)d >> 8], 1u);
            }
        }
        __syncthreads();
        if (t < NBINS) {
            s_base[t] = atomicAdd(&cursors[t * 16], s_cnt[t]);
            s_cnt[t] = 0u;               // becomes the within-block offset
        }
        __syncthreads();
#pragma unroll
        for (int i = 0; i < 8; ++i) {
            if (pk[i] != 0xFFFFFFFFu) {
                u32 bin = pk[i] >> 24;   // == dst>>8
                u32 off = s_base[bin] + atomicAdd(&s_cnt[bin], 1u);
                if (off < BINCAP) binbuf[bin * BINCAP + off] = pk[i];
            }
        }
    } else if (bid < NBINB + 6250) {
        int i = (bid - NBINB) * 256 + t; // 1.6M = 6.4M floats / 4
        float4 v = ((const float4*)nfeats)[i];
        ushort4 o;
        o.x = f2h(v.x); o.y = f2h(v.y); o.z = f2h(v.z); o.w = f2h(v.w);
        ((ushort4*)nf16)[i] = o;
    } else {
        int j = (bid - NBINB - 6250) * 256 + t;   // [0, 32768)
        const float* W = (j < 16384) ? W1 : W2;
        u16* T = (j < 16384) ? W1T : W2T;
        int jj = j & 16383;
        int n = jj >> 7, k = jj & 127;
        T[jj] = f2bf(W[k * 128 + n]);
    }
}

// ------- 2. per-(bin,half) bucket build: all pos atomics in LDS ---------
__global__ __launch_bounds__(256) void build_kernel(const u32* __restrict__ cursors,
                                                    const u32* __restrict__ binbuf,
                                                    u32* __restrict__ counts,
                                                    u16* __restrict__ edge16) {
    __shared__ u32 cnt[128];
    int t = threadIdx.x;
    if (t < 128) cnt[t] = 0u;
    __syncthreads();
    int b = blockIdx.x >> 1, half = blockIdx.x & 1;
    int n = (int)cursors[b * 16]; if (n > BINCAP) n = BINCAP;
    for (int i = t; i < n; i += 256) {
        u32 pk = binbuf[b * BINCAP + i];
        int dl = (int)((pk >> 16) & 0xFFu);
        if ((dl >> 7) == half) {
            u32 pos = atomicAdd(&cnt[dl & 127], 1u);
            if (pos < CAP) edge16[(((b << 8) + dl) << 6) + (int)pos] = (u16)(pk & 0xFFFFu);
        }
    }
    __syncthreads();
    if (t < 128) counts[(b << 8) + half * 128 + t] = cnt[t];
}

// ------- 3. gather: dedup + sum + combine -> X bf16 stashed in d_out ----
// One wave per dst. PAIR-OF-ROWS loads: lanes 0-31 read row 2j, lanes
// 32-63 read row 2j+1, dwordx2 (8B = 4 features) per lane -> one
// wave-load covers 512B (2 rows). 8 loads in flight = 16 rows/burst;
// avg dst (~15 kept rows) finishes in ONE burst. Halves are folded with
// shfl_xor(32) at the end. Tests instruction-rate vs fabric-BW bound.
__global__ __launch_bounds__(256) void gather_kernel(const u16* __restrict__ nf16,
                                                     const u32* __restrict__ counts,
                                                     const u16* __restrict__ edge16,
                                                     const float* __restrict__ alpha,
                                                     float* O) {
    __shared__ __align__(16) u32 s_kept[4][CAP];
    int w = threadIdx.x >> 6, lane = threadIdx.x & 63;
    int d = blockIdx.x * 4 + w;          // grid = NNODES/4 exactly
    int c = (int)counts[d];
    int cc = c < CAP ? c : CAP;
    const int lhalf = lane & 31;
    const bool hi = lane >= 32;
    const int lane8 = lhalf * 8;         // byte offset of this lane's 4 features
    const char* nfb = (const char*)nf16 + lane8;

    // issue dst row + alpha loads early; they complete under the dedup phase
    float al = 1.0f + alpha[0];
    uint2 rd = *(const uint2*)((const char*)nf16 + ((size_t)d << 8) + lane8);

    u32 si = 0xFFFFFFFFu;
    if (lane < cc) si = (u32)edge16[(d << 6) + lane];

    // kill lane if any earlier lane holds the same src
    unsigned long long kill = 0ull;
    for (int j = 0; j < cc - 1; ++j) {
        u32 sj = __builtin_amdgcn_readlane(si, j);       // SGPR broadcast
        unsigned long long eq = __ballot(si == sj);      // one v_cmp
        kill |= eq & ~((2ull << j) - 1ull);              // lanes > j (SALU)
    }
    bool keep = (lane < cc) && !((kill >> lane) & 1ull);
    unsigned long long m = __ballot(keep);
    int nk = __popcll(m);
    int nkp = (nk + 15) & ~15;           // pad to multiple of 16 (<= 64)
    if (keep) s_kept[w][__popcll(m & ((1ull << lane) - 1ull))] = si << 8;  // byte off
    if (lane >= nk && lane < nkp) s_kept[w][lane] = ((u32)NNODES << 8);    // zero row
    __builtin_amdgcn_wave_barrier();     // wave-private LDS: no __syncthreads

    f32x2 accA = (f32x2){0.f, 0.f};      // features 4*lhalf+0, +1 (partial: own half's rows)
    f32x2 accB = (f32x2){0.f, 0.f};      // features 4*lhalf+2, +3
    for (int i = 0; i < nkp; i += 16) {  // 8 paired loads = 16 rows in flight
        int4 q0 = *(const int4*)&s_kept[w][i];
        int4 q1 = *(const int4*)&s_kept[w][i + 4];
        int4 q2 = *(const int4*)&s_kept[w][i + 8];
        int4 q3 = *(const int4*)&s_kept[w][i + 12];
        u32 o0 = hi ? (u32)q0.y : (u32)q0.x;
        u32 o1 = hi ? (u32)q0.w : (u32)q0.z;
        u32 o2 = hi ? (u32)q1.y : (u32)q1.x;
        u32 o3 = hi ? (u32)q1.w : (u32)q1.z;
        u32 o4 = hi ? (u32)q2.y : (u32)q2.x;
        u32 o5 = hi ? (u32)q2.w : (u32)q2.z;
        u32 o6 = hi ? (u32)q3.y : (u32)q3.x;
        u32 o7 = hi ? (u32)q3.w : (u32)q3.z;
        uint2 r0 = *(const uint2*)(nfb + o0);
        uint2 r1 = *(const uint2*)(nfb + o1);
        uint2 r2 = *(const uint2*)(nfb + o2);
        uint2 r3 = *(const uint2*)(nfb + o3);
        uint2 r4 = *(const uint2*)(nfb + o4);
        uint2 r5 = *(const uint2*)(nfb + o5);
        uint2 r6 = *(const uint2*)(nfb + o6);
        uint2 r7 = *(const uint2*)(nfb + o7);
        f32x2 tA0 = (h2v2(r0.x) + h2v2(r1.x)) + (h2v2(r2.x) + h2v2(r3.x));
        f32x2 tA1 = (h2v2(r4.x) + h2v2(r5.x)) + (h2v2(r6.x) + h2v2(r7.x));
        f32x2 tB0 = (h2v2(r0.y) + h2v2(r1.y)) + (h2v2(r2.y) + h2v2(r3.y));
        f32x2 tB1 = (h2v2(r4.y) + h2v2(r5.y)) + (h2v2(r6.y) + h2v2(r7.y));
        accA += tA0 + tA1;
        accB += tB0 + tB1;
    }

    // fold the two halves: both end up with the full sums
    accA.x += __shfl_xor(accA.x, 32);
    accA.y += __shfl_xor(accA.y, 32);
    accB.x += __shfl_xor(accB.x, 32);
    accB.y += __shfl_xor(accB.y, 32);

    if (!hi) {                           // 32 lanes write the 256B X row
        f32x2 dv0 = h2v2(rd.x), dv1 = h2v2(rd.y);
        u32 plo = (u32)f2bf(fmaf(al, dv0.x, accA.x)) | ((u32)f2bf(fmaf(al, dv0.y, accA.y)) << 16);
        u32 phi = (u32)f2bf(fmaf(al, dv1.x, accB.x)) | ((u32)f2bf(fmaf(al, dv1.y, accB.y)) << 16);
        *(uint2*)((char*)O + (size_t)d * 512 + lane8) = make_uint2(plo, phi);
    }
}

// ------- 4. fused MFMA MLP: O = relu(X@W1+b1)@W2 + b2 -------------------
// X (bf16) read from d_out's own rows (interleaved stash), then overwritten.
__global__ __launch_bounds__(256) void mlp_kernel(const u16* __restrict__ W1T,
                                                  const float* __restrict__ b1,
                                                  const u16* __restrict__ W2T,
                                                  const float* __restrict__ b2,
                                                  float* O,
                                                  int M) {
    __shared__ __align__(16) u16 sA[64][136];
    __shared__ __align__(16) u16 sW[128][136];
    __shared__ float sB[128];

    const int tid = threadIdx.x;
    const int m0 = blockIdx.x * 64;
    const int wave = tid >> 6, lane = tid & 63;
    const int lrow = lane & 15, quad = lane >> 4;
    const int warow = wave * 16;

    // stage W1T (32 KB, L2-hot): 2048 uint4
    for (int i = tid; i < 2048; i += 256) {
        int n = i >> 4, c8 = i & 15;
        *(uint4*)((char*)(&sW[0][0]) + n * 272 + c8 * 16) = ((const uint4*)W1T)[i];
    }
    if (tid < 128) sB[tid] = b1[tid];

    // stage X tile from d_out's interleaved stash (row r = first 256B of
    // O row r's 512B slot); this block only ever writes these same rows.
    for (int i = tid; i < 1024; i += 256) {
        int r = i >> 4, c8 = i & 15;
        int gr = m0 + r;
        uint4 v = make_uint4(0u, 0u, 0u, 0u);
        if (gr < M) v = *(const uint4*)((const char*)O + (size_t)gr * 512 + c8 * 16);
        *(uint4*)((char*)(&sA[0][0]) + r * 272 + c8 * 16) = v;
    }
    __syncthreads();

    {   // phase A: H = relu(X@W1 + b1) -> back into sA (own rows only)
        f32x4 acc[8];
#pragma unroll
        for (int nt = 0; nt < 8; ++nt) acc[nt] = (f32x4){0.f, 0.f, 0.f, 0.f};
#pragma unroll
        for (int kk = 0; kk < 4; ++kk) {
            bf16x8 a = *(const bf16x8*)((const char*)(&sA[0][0]) + (warow + lrow) * 272 + kk * 64 + quad * 16);
#pragma unroll
            for (int nt = 0; nt < 8; ++nt) {
                bf16x8 b = *(const bf16x8*)((const char*)(&sW[0][0]) + (nt * 16 + lrow) * 272 + kk * 64 + quad * 16);
                acc[nt] = __builtin_amdgcn_mfma_f32_16x16x32_bf16(a, b, acc[nt], 0, 0, 0);
            }
        }
#pragma unroll
        for (int nt = 0; nt < 8; ++nt) {
            int col = nt * 16 + lrow;
            float bc = sB[col];
#pragma unroll
            for (int r = 0; r < 4; ++r)
                sA[warow + quad * 4 + r][col] = f2bf(fmaxf(acc[nt][r] + bc, 0.0f));
        }
    }
    __syncthreads();

    // stage W2T + b2
    for (int i = tid; i < 2048; i += 256) {
        int n = i >> 4, c8 = i & 15;
        *(uint4*)((char*)(&sW[0][0]) + n * 272 + c8 * 16) = ((const uint4*)W2T)[i];
    }
    if (tid < 128) sB[tid] = b2[tid];
    __syncthreads();

    {   // phase B: O = H@W2 + b2, store f32 (overwrites the X stash rows)
        f32x4 acc[8];
#pragma unroll
        for (int nt = 0; nt < 8; ++nt) acc[nt] = (f32x4){0.f, 0.f, 0.f, 0.f};
#pragma unroll
        for (int kk = 0; kk < 4; ++kk) {
            bf16x8 a = *(const bf16x8*)((const char*)(&sA[0][0]) + (warow + lrow) * 272 + kk * 64 + quad * 16);
#pragma unroll
            for (int nt = 0; nt < 8; ++nt) {
                bf16x8 b = *(const bf16x8*)((const char*)(&sW[0][0]) + (nt * 16 + lrow) * 272 + kk * 64 + quad * 16);
                acc[nt] = __builtin_amdgcn_mfma_f32_16x16x32_bf16(a, b, acc[nt], 0, 0, 0);
            }
        }
#pragma unroll
        for (int nt = 0; nt < 8; ++nt) {
            int col = nt * 16 + lrow;
            float bc = sB[col];
#pragma unroll
            for (int r = 0; r < 4; ++r) {
                int grow = m0 + warow + quad * 4 + r;
                if (grow < M) O[(size_t)grow * DF + col] = acc[nt][r] + bc;
            }
        }
    }
}

extern "C" void kernel_launch(void* const* d_in, const int* in_sizes, int n_in,
                              void* d_out, int out_size, void* d_ws, size_t ws_size,
                              hipStream_t stream) {
    const float* nfeats = (const float*)d_in[0];
    const void*  src    = d_in[1];
    const void*  dst    = d_in[2];
    const float* W1     = (const float*)d_in[3];
    const float* b1     = (const float*)d_in[4];
    const float* W2     = (const float*)d_in[5];
    const float* b2     = (const float*)d_in[6];
    const float* alpha  = (const float*)d_in[7];

    // Workspace (23.5 MB; 26.4 MB proven safe). X lives in d_out (interleaved).
    //   counts  u32[50176]           @ 0
    //   edge16  u16[50176*64]        @ 200704     (6.4 MB u16 buckets)
    //   flag    u32                  @ 6623232
    //   W1T bf16 u16[16384]          @ 6623248
    //   W2T bf16 u16[16384]          @ 6656016
    //   nf16 fp16 u16[50001*128]     @ 6688784    (12.8 MB + 256B zero pad row)
    //   binbuf  u32[196*5120]        @ 19489040   (4.0 MB)
    //   cursors u32[196*16]          @ 23503120   (64B-padded per bin)
    char* ws = (char*)d_ws;
    u32* counts   = (u32*)ws;
    u16* edge16   = (u16*)(ws + 200704);
    u32* flag     = (u32*)(ws + 6623232);
    u16* W1T      = (u16*)(ws + 6623248);
    u16* W2T      = (u16*)(ws + 6656016);
    u16* nf16     = (u16*)(ws + 6688784);
    u32* binbuf   = (u32*)(ws + 19489040);
    u32* cursors  = (u32*)(ws + 23503120);

    init_kernel<<<1, 256, 0, stream>>>((const u32*)src, flag, cursors, nf16);
    prepbin_kernel<<<NBINB + 6250 + 128, 256, 0, stream>>>(src, dst, flag, cursors, binbuf,
                                                           nfeats, W1, W2, nf16, W1T, W2T);
    build_kernel<<<NBINS * 2, 256, 0, stream>>>(cursors, binbuf, counts, edge16);
    gather_kernel<<<NNODES / 4, 256, 0, stream>>>(nf16, counts, edge16, alpha, (float*)d_out);
    mlp_kernel<<<(NNODES + 63) / 64, 256, 0, stream>>>(W1T, b1, W2T, b2, (float*)d_out, NNODES);
}